// Round 2
// baseline (237.452 us; speedup 1.0000x reference)
//
#include <hip/hip_runtime.h>
#include <hip/hip_cooperative_groups.h>
#include <math.h>

namespace cg = cooperative_groups;

#define BATCH 32
#define NGT 20
#define HWA 10647
#define NCLS 80
#define NMATCH 32                 // one match block per batch
#define NDENSE 333                // 333*256 threads >= 85176 float4s
#define NBLK (NMATCH + NDENSE)    // 365 blocks; 45KB LDS -> 3/CU -> 768 cap
#define TOT_F4 ((BATCH * HWA) / 4)  // 340704/4 = 85176 (exact)
#define FP16_EPS 0.0009765625f
#define BCE_EPS 1e-6f

__device__ __constant__ float ANCS[9][2] = {
    {0.024f, 0.031f}, {0.038f, 0.072f}, {0.079f, 0.055f},
    {0.072f, 0.147f}, {0.149f, 0.108f}, {0.142f, 0.286f},
    {0.279f, 0.216f}, {0.375f, 0.476f}, {0.897f, 0.784f}};

// Fast device math (v_exp/v_log/v_rcp). Verified absmax 0.0 in prior rounds
// vs threshold 1.79 — huge slack.
__device__ __forceinline__ float flog(float x) { return __logf(x); }
__device__ __forceinline__ float fsig(float x) {
  return __builtin_amdgcn_rcpf(1.0f + __expf(-x));
}

// Matching state per HWA row, packed into one int resolved by atomicMax:
//   bits [31:16] = priority (2p+1 for the "-1" col0 write, 2p+2 for the
//                  positive full-row write at scan step p)
//   bit  [15]    = is-positive-write
//   bits [7:0]   = rec = i*9 + a  (GT index i, anchor id a)
// cell == 0 <=> never written <=> gconf == 0 (negative row).
// atomicMax reproduces the reference scan's last-writer-wins exactly
// (verified absmax 0.0 through R1). Structure (R1, unchanged numerics):
// 32 match blocks (one per batch, full-HWA cell array in LDS) + 333 dense
// blocks streaming sigmoid(pconf)^2 over ALL rows; special rows get a
// sparse correction. NEW in R2: single cooperative launch — grid.sync()
// replaces the second dispatch; block 0 folds the 365 partials and writes
// the scalar loss. Removes one dispatch + the inter-kernel drain bubble.

__global__ __launch_bounds__(256) void yolo_fused(
    const float* __restrict__ pconf,   // [B, HWA, 1]
    const float* __restrict__ pcls,    // [B, HWA, 80]
    const float* __restrict__ ptxywh,  // [B, HWA, 4]
    const float* __restrict__ gbox,    // [B, NGT, 4]
    const int* __restrict__ glab,      // [B, NGT]
    float* __restrict__ part,          // [8*NMATCH + NDENSE] partials
    float* __restrict__ out)           // [1]
{
  const int tid = threadIdx.x;
  const int blk = blockIdx.x;

  __shared__ int cell[HWA];            // 42588 B
  __shared__ int pos_list[256];
  __shared__ int special[256];
  __shared__ float s_cx[NGT], s_cy[NGT], s_w[NGT], s_h[NGT], s_wt[NGT];
  __shared__ int s_a[NGT], s_lab[NGT], s_idx[NGT][3];
  __shared__ int s_np, s_nsp;
  __shared__ float red[4][8];

  if (blk >= NMATCH) {
    // ---- dense conf pass: streaming sum of sigmoid(pconf)^2, all rows ----
    int f = (blk - NMATCH) * 256 + tid;
    float sum = 0.f;
    if (f < TOT_F4) {
      float4 v = ((const float4*)pconf)[f];
      float s0 = fsig(v.x), s1 = fsig(v.y), s2 = fsig(v.z), s3 = fsig(v.w);
      sum = s0 * s0 + s1 * s1 + s2 * s2 + s3 * s3;
    }
    int lane = tid & 63, wv = tid >> 6;
    for (int o = 32; o > 0; o >>= 1) sum += __shfl_down(sum, o, 64);
    if (lane == 0) red[wv][0] = sum;
    __syncthreads();
    if (tid == 0)
      part[8 * NMATCH + (blk - NMATCH)] =
          red[0][0] + red[1][0] + red[2][0] + red[3][0];
  } else {
    // ================= match path: batch b = blk =================
    const int b = blk;

    for (int r = tid; r < HWA; r += 256) cell[r] = 0;
    if (tid == 0) { s_np = 0; s_nsp = 0; }
    if (tid < NGT) {
      const float* gb = gbox + (b * NGT + tid) * 4;
      float l = gb[0], t = gb[1], r = gb[2], bo = gb[3];
      float cx = (l + r) * 0.5f, cy = (t + bo) * 0.5f;
      float w = r - l, h = bo - t;
      s_cx[tid] = cx; s_cy[tid] = cy; s_w[tid] = w; s_h[tid] = h;
      s_wt[tid] = 2.0f - w * h;
      s_lab[tid] = glab[b * NGT + tid];
      // argmax over 9 ratios: precise division (decision bits must match).
      float best = -1e30f; int bi = 0;
      for (int a = 0; a < 9; ++a) {
        float inter = fminf(w, ANCS[a][0]) * fminf(h, ANCS[a][1]);
        float uni = w * h + ANCS[a][0] * ANCS[a][1] - inter;
        float ratio = inter / uni;
        if (ratio > best) { best = ratio; bi = a; }  // first max == argmax
      }
      s_a[tid] = bi;
      const int GR[3] = {52, 26, 13};
      const int OF[3] = {0, 2704, 3380};
      for (int j = 0; j < 3; ++j) {
        int col = (int)(cx * (float)GR[j]);   // trunc, matches astype(int32)
        int row = (int)(cy * (float)GR[j]);
        s_idx[tid][j] = (OF[j] + row * GR[j] + col) * 3;
      }
    }
    __syncthreads();

    // ---- the 400-step scan via priority atomicMax, full array ----
    for (int p = tid; p < NGT * NGT; p += 256) {
      int i = p / NGT, k = p - i * NGT;
      int a = s_a[k];
      int ceng = a / 3;
      int pn = (2 * p + 1) << 16;
      int pp = ((2 * p + 2) << 16) | (1 << 15) | (i * 9 + a);
      for (int j = 0; j < 3; ++j) {
        int idx = s_idx[i][j];
        atomicMax(&cell[idx], pn);
        atomicMax(&cell[idx + 1], pn);
        atomicMax(&cell[idx + 2], pn);
        if (ceng == j) atomicMax(&cell[idx + (a - ceng * 3)], pp);
      }
    }
    __syncthreads();

    // ---- compact special rows (cell != 0) and positives ----
    // <= 20 GT * 9 window cells = 180 distinct -> 256 slots is safe.
    for (int r = tid; r < HWA; r += 256) {
      int c = cell[r];
      if (c != 0) {
        int slot = atomicAdd(&s_nsp, 1);
        int pk = ((c & 0xFF) << 16) | r;
        if (c & (1 << 15)) {
          pk |= (int)0x80000000;
          int ps = atomicAdd(&s_np, 1);
          pos_list[ps] = ((c & 0xFF) << 16) | r;
        }
        special[slot] = pk;
      }
    }
    __syncthreads();
    const int NSP = s_nsp, P = s_np;

    // ---- sparse conf corrections over special rows ----
    float possum = 0.f, negcorr = 0.f; int cnt_pos = 0;
    for (int q = tid; q < NSP; q += 256) {
      int pk = special[q];
      int r = pk & 0xFFFF;
      float s = fsig(pconf[(size_t)b * HWA + r]);
      negcorr += s * s;                      // this row is NOT a negative
      if (pk < 0) {                          // positive row
        float d = s - 1.0f; possum += d * d; cnt_pos++;
      }
    }

    // ---- sparse class BCE over positive rows ----
    float cls_sum = 0.f;
    for (int idx = tid; idx < P * NCLS; idx += 256) {
      int pr = idx / NCLS, c = idx - pr * NCLS;
      int pk = pos_list[pr];
      int r = pk & 0xFFFF, rec = pk >> 16;
      int i = rec / 9;
      int lab = s_lab[i] - 1;
      float x = pcls[((size_t)b * HWA + r) * NCLS + c];
      float s = fsig(x);
      s = fminf(fmaxf(s, BCE_EPS), 1.0f - BCE_EPS);
      float g = (c == lab) ? 1.0f : 0.0f;
      cls_sum += -(g * flog(s) + (1.0f - g) * flog(1.0f - s));
    }

    // ---- sparse txty (BCE) + twth (L2) over positive rows ----
    float txty_sum = 0.f, twth_sum = 0.f;
    for (int q = tid; q < P; q += 256) {
      int pk = pos_list[q];
      int r = pk & 0xFFFF, rec = pk >> 16;
      int i = rec / 9, a = rec - i * 9;
      int ceng = a / 3;
      const int GR[3] = {52, 26, 13};
      float grid = (float)GR[ceng];
      float cx = s_cx[i], cy = s_cy[i];
      int col = (int)(cx * grid), row = (int)(cy * grid);
      float tx = (cx - (float)col / grid) * grid;
      float ty = (cy - (float)row / grid) * grid;
      float twx = flog(s_w[i] / ANCS[a][0]);
      float twy = flog(s_h[i] / ANCS[a][1]);
      float wgt = s_wt[i];
      const float* pt = ptxywh + ((size_t)b * HWA + r) * 4;
      float s0 = fsig(pt[0]);
      float s1 = fsig(pt[1]);
      s0 = fminf(fmaxf(s0, BCE_EPS), 1.0f - BCE_EPS);
      s1 = fminf(fmaxf(s1, BCE_EPS), 1.0f - BCE_EPS);
      float b0 = -(tx * flog(s0) + (1.0f - tx) * flog(1.0f - s0));
      float b1 = -(ty * flog(s1) + (1.0f - ty) * flog(1.0f - s1));
      txty_sum += (b0 + b1) * wgt;
      float d2 = pt[2] - twx, d3 = pt[3] - twy;
      twth_sum += (d2 * d2 + d3 * d3) * wgt;
    }

    // ---- block reduce 6 partials, finalize per-batch row ----
    float v[6] = {possum, negcorr, (float)cnt_pos, cls_sum, txty_sum, twth_sum};
    int lane = tid & 63, wv = tid >> 6;
    for (int m = 0; m < 6; ++m) {
      float x = v[m];
      for (int o = 32; o > 0; o >>= 1) x += __shfl_down(x, o, 64);
      if (lane == 0) red[wv][m] = x;
    }
    __syncthreads();
    if (tid == 0) {
      float t[6];
      for (int m = 0; m < 6; ++m)
        t[m] = red[0][m] + red[1][m] + red[2][m] + red[3][m];
      float np = fmaxf(t[2], FP16_EPS);   // nums_pos clamp, per batch
      float rnp = 1.0f / np;
      float* w = part + b * 8;
      w[0] = t[0];            // sum_pos
      w[1] = t[1];            // neg correction (sum s^2 over special rows)
      w[2] = t[2];            // cnt_pos
      w[3] = (float)NSP;      // n_special (pos + ignore rows)
      w[4] = t[3] * rnp;      // l_cls_b
      w[5] = t[4] * rnp;      // l_txty_b
      w[6] = t[5] * rnp;      // l_twth_b
    }
  }

  // ---- grid-wide sync, then block 0 folds all partials in-kernel ----
  __threadfence();            // cross-XCD visibility of part[] writes
  cg::this_grid().sync();

  if (blk == 0) {
    float acc[8];
#pragma unroll
    for (int m = 0; m < 8; ++m) acc[m] = 0.f;
    for (int d = tid; d < NDENSE; d += 256) acc[0] += part[8 * NMATCH + d];
    if (tid < NMATCH) {
      const float* w = part + tid * 8;
#pragma unroll
      for (int m = 0; m < 7; ++m) acc[m + 1] = w[m];
    }
    int lane = tid & 63, wv = tid >> 6;
#pragma unroll
    for (int m = 0; m < 8; ++m) {
      float x = acc[m];
      for (int o = 32; o > 0; o >>= 1) x += __shfl_down(x, o, 64);
      if (lane == 0) red[wv][m] = x;   // red[] reuse is safe post grid-sync
    }
    __syncthreads();
    if (tid == 0) {
      float s[8];
#pragma unroll
      for (int m = 0; m < 8; ++m)
        s[m] = red[0][m] + red[1][m] + red[2][m] + red[3][m];
      float dense = s[0], possum = s[1], negcorr = s[2];
      float cntpos = s[3], nsp = s[4];
      float sum_neg = dense - negcorr;
      float cnt_neg = (float)(BATCH * HWA) - nsp;
      out[0] = possum / cntpos * 30.0f + sum_neg / cnt_neg * 30.0f +
               (s[5] + s[6] + s[7]) * (1.0f / (float)BATCH);
    }
  }
}

extern "C" void kernel_launch(void* const* d_in, const int* in_sizes, int n_in,
                              void* d_out, int out_size, void* d_ws,
                              size_t ws_size, hipStream_t stream) {
  const float* pconf  = (const float*)d_in[0];
  const float* pcls   = (const float*)d_in[1];
  const float* ptxywh = (const float*)d_in[2];
  const float* gbox   = (const float*)d_in[3];
  const int*   glab   = (const int*)d_in[4];
  float* part = (float*)d_ws;  // 8*NMATCH + NDENSE floats ~ 2.4 KB
  float* outp = (float*)d_out;

  void* args[] = {(void*)&pconf, (void*)&pcls, (void*)&ptxywh,
                  (void*)&gbox,  (void*)&glab, (void*)&part, (void*)&outp};
  hipLaunchCooperativeKernel((void*)yolo_fused, dim3(NBLK), dim3(256),
                             args, 0, stream);
}

// Round 3
// 160.748 us; speedup vs baseline: 1.4772x; 1.4772x over previous
//
#include <hip/hip_runtime.h>
#include <math.h>

#define BATCH 32
#define NGT 20
#define HWA 10647
#define NCLS 80
#define NMATCH 32                   // one match block per batch
#define NDENSE 167                  // 167*256*2 = 85504 >= 85176 float4s
#define NBLK (NMATCH + NDENSE)      // 199 blocks — fits one scheduling wave
#define TOT_F4 ((BATCH * HWA) / 4)  // 340704/4 = 85176 (exact)
#define PART_N (8 * NMATCH + NDENSE)
#define FP16_EPS 0.0009765625f
#define BCE_EPS 1e-6f

__device__ __constant__ float ANCS[9][2] = {
    {0.024f, 0.031f}, {0.038f, 0.072f}, {0.079f, 0.055f},
    {0.072f, 0.147f}, {0.149f, 0.108f}, {0.142f, 0.286f},
    {0.279f, 0.216f}, {0.375f, 0.476f}, {0.897f, 0.784f}};

// Fast device math (v_exp/v_log/v_rcp). Verified absmax 0.0 in prior rounds
// vs threshold 1.79 — huge slack.
__device__ __forceinline__ float flog(float x) { return __logf(x); }
__device__ __forceinline__ float fsig(float x) {
  return __builtin_amdgcn_rcpf(1.0f + __expf(-x));
}

// Matching state per HWA row, packed into one int resolved by atomicMax:
//   bits [31:16] = priority (2p+1 for the "-1" col0 write, 2p+2 for the
//                  positive full-row write at scan step p)
//   bit  [15]    = is-positive-write
//   bits [7:0]   = rec = i*9 + a  (GT index i, anchor id a)
// cell == 0 <=> never written <=> gconf == 0 (negative row).
// atomicMax reproduces the reference scan's last-writer-wins exactly
// (verified absmax 0.0 through R2).
//
// Structure: 32 match blocks (one per batch, full-HWA cell array in LDS) +
// 167 dense blocks streaming sigmoid(pconf)^2 over ALL rows (2 float4 each);
// matched rows get a sparse correction. R3: single NON-cooperative dispatch;
// completion via last-block-done (threadfence + agent-scope counter). R2's
// cooperative grid.sync() measured ~75 us of pure barrier cost — reverted.
// Counter is zeroed by a hipMemsetAsync node (workspace is poisoned).

__global__ __launch_bounds__(256) void yolo_fused(
    const float* __restrict__ pconf,   // [B, HWA, 1]
    const float* __restrict__ pcls,    // [B, HWA, 80]
    const float* __restrict__ ptxywh,  // [B, HWA, 4]
    const float* __restrict__ gbox,    // [B, NGT, 4]
    const int* __restrict__ glab,      // [B, NGT]
    float* __restrict__ part,          // [PART_N] partials
    int* __restrict__ cnt,             // [1] arrival counter (pre-zeroed)
    float* __restrict__ out)           // [1]
{
  const int tid = threadIdx.x;
  const int blk = blockIdx.x;

  __shared__ int cell[HWA];            // 42588 B
  __shared__ int pos_list[256];
  __shared__ int special[256];
  __shared__ float s_cx[NGT], s_cy[NGT], s_w[NGT], s_h[NGT], s_wt[NGT];
  __shared__ int s_a[NGT], s_lab[NGT], s_idx[NGT][3];
  __shared__ int s_np, s_nsp;
  __shared__ float red[4][8];
  __shared__ int s_won;

  if (blk >= NMATCH) {
    // ---- dense conf pass: streaming sum of sigmoid(pconf)^2, all rows ----
    int d = blk - NMATCH;
    int f0 = d * 256 + tid;
    int f1 = f0 + NDENSE * 256;
    float sum = 0.f;
    if (f0 < TOT_F4) {
      float4 v = ((const float4*)pconf)[f0];
      float s0 = fsig(v.x), s1 = fsig(v.y), s2 = fsig(v.z), s3 = fsig(v.w);
      sum += s0 * s0 + s1 * s1 + s2 * s2 + s3 * s3;
    }
    if (f1 < TOT_F4) {
      float4 v = ((const float4*)pconf)[f1];
      float s0 = fsig(v.x), s1 = fsig(v.y), s2 = fsig(v.z), s3 = fsig(v.w);
      sum += s0 * s0 + s1 * s1 + s2 * s2 + s3 * s3;
    }
    int lane = tid & 63, wv = tid >> 6;
    for (int o = 32; o > 0; o >>= 1) sum += __shfl_down(sum, o, 64);
    if (lane == 0) red[wv][0] = sum;
    __syncthreads();
    if (tid == 0)
      part[8 * NMATCH + d] = red[0][0] + red[1][0] + red[2][0] + red[3][0];
  } else {
    // ================= match path: batch b = blk =================
    const int b = blk;

    for (int r = tid; r < HWA; r += 256) cell[r] = 0;
    if (tid == 0) { s_np = 0; s_nsp = 0; }
    if (tid < NGT) {
      const float* gb = gbox + (b * NGT + tid) * 4;
      float l = gb[0], t = gb[1], r = gb[2], bo = gb[3];
      float cx = (l + r) * 0.5f, cy = (t + bo) * 0.5f;
      float w = r - l, h = bo - t;
      s_cx[tid] = cx; s_cy[tid] = cy; s_w[tid] = w; s_h[tid] = h;
      s_wt[tid] = 2.0f - w * h;
      s_lab[tid] = glab[b * NGT + tid];
      // argmax over 9 ratios: precise division (decision bits must match).
      float best = -1e30f; int bi = 0;
      for (int a = 0; a < 9; ++a) {
        float inter = fminf(w, ANCS[a][0]) * fminf(h, ANCS[a][1]);
        float uni = w * h + ANCS[a][0] * ANCS[a][1] - inter;
        float ratio = inter / uni;
        if (ratio > best) { best = ratio; bi = a; }  // first max == argmax
      }
      s_a[tid] = bi;
      const int GR[3] = {52, 26, 13};
      const int OF[3] = {0, 2704, 3380};
      for (int j = 0; j < 3; ++j) {
        int col = (int)(cx * (float)GR[j]);   // trunc, matches astype(int32)
        int row = (int)(cy * (float)GR[j]);
        s_idx[tid][j] = (OF[j] + row * GR[j] + col) * 3;
      }
    }
    __syncthreads();

    // ---- the 400-step scan via priority atomicMax, full array ----
    for (int p = tid; p < NGT * NGT; p += 256) {
      int i = p / NGT, k = p - i * NGT;
      int a = s_a[k];
      int ceng = a / 3;
      int pn = (2 * p + 1) << 16;
      int pp = ((2 * p + 2) << 16) | (1 << 15) | (i * 9 + a);
      for (int j = 0; j < 3; ++j) {
        int idx = s_idx[i][j];
        atomicMax(&cell[idx], pn);
        atomicMax(&cell[idx + 1], pn);
        atomicMax(&cell[idx + 2], pn);
        if (ceng == j) atomicMax(&cell[idx + (a - ceng * 3)], pp);
      }
    }
    __syncthreads();

    // ---- compact special rows (cell != 0) and positives ----
    // <= 20 GT * 9 window cells = 180 distinct -> 256 slots is safe.
    for (int r = tid; r < HWA; r += 256) {
      int c = cell[r];
      if (c != 0) {
        int slot = atomicAdd(&s_nsp, 1);
        int pk = ((c & 0xFF) << 16) | r;
        if (c & (1 << 15)) {
          pk |= (int)0x80000000;
          int ps = atomicAdd(&s_np, 1);
          pos_list[ps] = ((c & 0xFF) << 16) | r;
        }
        special[slot] = pk;
      }
    }
    __syncthreads();
    const int NSP = s_nsp, P = s_np;

    // ---- sparse conf corrections over special rows ----
    float possum = 0.f, negcorr = 0.f; int cnt_pos = 0;
    for (int q = tid; q < NSP; q += 256) {
      int pk = special[q];
      int r = pk & 0xFFFF;
      float s = fsig(pconf[(size_t)b * HWA + r]);
      negcorr += s * s;                      // this row is NOT a negative
      if (pk < 0) {                          // positive row
        float d = s - 1.0f; possum += d * d; cnt_pos++;
      }
    }

    // ---- sparse class BCE over positive rows ----
    float cls_sum = 0.f;
    for (int idx = tid; idx < P * NCLS; idx += 256) {
      int pr = idx / NCLS, c = idx - pr * NCLS;
      int pk = pos_list[pr];
      int r = pk & 0xFFFF, rec = pk >> 16;
      int i = rec / 9;
      int lab = s_lab[i] - 1;
      float x = pcls[((size_t)b * HWA + r) * NCLS + c];
      float s = fsig(x);
      s = fminf(fmaxf(s, BCE_EPS), 1.0f - BCE_EPS);
      float g = (c == lab) ? 1.0f : 0.0f;
      cls_sum += -(g * flog(s) + (1.0f - g) * flog(1.0f - s));
    }

    // ---- sparse txty (BCE) + twth (L2) over positive rows ----
    float txty_sum = 0.f, twth_sum = 0.f;
    for (int q = tid; q < P; q += 256) {
      int pk = pos_list[q];
      int r = pk & 0xFFFF, rec = pk >> 16;
      int i = rec / 9, a = rec - i * 9;
      int ceng = a / 3;
      const int GR[3] = {52, 26, 13};
      float grid = (float)GR[ceng];
      float cx = s_cx[i], cy = s_cy[i];
      int col = (int)(cx * grid), row = (int)(cy * grid);
      float tx = (cx - (float)col / grid) * grid;
      float ty = (cy - (float)row / grid) * grid;
      float twx = flog(s_w[i] / ANCS[a][0]);
      float twy = flog(s_h[i] / ANCS[a][1]);
      float wgt = s_wt[i];
      const float* pt = ptxywh + ((size_t)b * HWA + r) * 4;
      float s0 = fsig(pt[0]);
      float s1 = fsig(pt[1]);
      s0 = fminf(fmaxf(s0, BCE_EPS), 1.0f - BCE_EPS);
      s1 = fminf(fmaxf(s1, BCE_EPS), 1.0f - BCE_EPS);
      float b0 = -(tx * flog(s0) + (1.0f - tx) * flog(1.0f - s0));
      float b1 = -(ty * flog(s1) + (1.0f - ty) * flog(1.0f - s1));
      txty_sum += (b0 + b1) * wgt;
      float d2 = pt[2] - twx, d3 = pt[3] - twy;
      twth_sum += (d2 * d2 + d3 * d3) * wgt;
    }

    // ---- block reduce 6 partials, finalize per-batch row ----
    float v[6] = {possum, negcorr, (float)cnt_pos, cls_sum, txty_sum, twth_sum};
    int lane = tid & 63, wv = tid >> 6;
    for (int m = 0; m < 6; ++m) {
      float x = v[m];
      for (int o = 32; o > 0; o >>= 1) x += __shfl_down(x, o, 64);
      if (lane == 0) red[wv][m] = x;
    }
    __syncthreads();
    if (tid == 0) {
      float t[6];
      for (int m = 0; m < 6; ++m)
        t[m] = red[0][m] + red[1][m] + red[2][m] + red[3][m];
      float np = fmaxf(t[2], FP16_EPS);   // nums_pos clamp, per batch
      float rnp = 1.0f / np;
      float* w = part + b * 8;
      w[0] = t[0];            // sum_pos
      w[1] = t[1];            // neg correction (sum s^2 over special rows)
      w[2] = t[2];            // cnt_pos
      w[3] = (float)NSP;      // n_special (pos + ignore rows)
      w[4] = t[3] * rnp;      // l_cls_b
      w[5] = t[4] * rnp;      // l_txty_b
      w[6] = t[5] * rnp;      // l_twth_b
    }
  }

  // ---- last-block-done: release partials, count arrival, winner folds ----
  if (tid == 0) {
    __threadfence();   // agent-scope release of this block's part[] row
    int prev = __hip_atomic_fetch_add(cnt, 1, __ATOMIC_ACQ_REL,
                                      __HIP_MEMORY_SCOPE_AGENT);
    s_won = (prev == NBLK - 1) ? 1 : 0;
  }
  __syncthreads();
  if (!s_won) return;

  __threadfence();     // acquire side for all lanes of the winner block
  float acc[8];
#pragma unroll
  for (int m = 0; m < 8; ++m) acc[m] = 0.f;
  if (tid < NDENSE)    // agent-scope loads bypass stale L1/L2 (XCD rule)
    acc[0] = __hip_atomic_load(&part[8 * NMATCH + tid], __ATOMIC_RELAXED,
                               __HIP_MEMORY_SCOPE_AGENT);
  if (tid < NMATCH) {
#pragma unroll
    for (int m = 0; m < 7; ++m)
      acc[m + 1] = __hip_atomic_load(&part[tid * 8 + m], __ATOMIC_RELAXED,
                                     __HIP_MEMORY_SCOPE_AGENT);
  }
  int lane = tid & 63, wv = tid >> 6;
#pragma unroll
  for (int m = 0; m < 8; ++m) {
    float x = acc[m];
    for (int o = 32; o > 0; o >>= 1) x += __shfl_down(x, o, 64);
    if (lane == 0) red[wv][m] = x;   // red[] reuse safe post-syncthreads
  }
  __syncthreads();
  if (tid == 0) {
    float s[8];
#pragma unroll
    for (int m = 0; m < 8; ++m)
      s[m] = red[0][m] + red[1][m] + red[2][m] + red[3][m];
    float dense = s[0], possum = s[1], negcorr = s[2];
    float cntpos = s[3], nsp = s[4];
    float sum_neg = dense - negcorr;
    float cnt_neg = (float)(BATCH * HWA) - nsp;
    out[0] = possum / cntpos * 30.0f + sum_neg / cnt_neg * 30.0f +
             (s[5] + s[6] + s[7]) * (1.0f / (float)BATCH);
  }
}

extern "C" void kernel_launch(void* const* d_in, const int* in_sizes, int n_in,
                              void* d_out, int out_size, void* d_ws,
                              size_t ws_size, hipStream_t stream) {
  const float* pconf  = (const float*)d_in[0];
  const float* pcls   = (const float*)d_in[1];
  const float* ptxywh = (const float*)d_in[2];
  const float* gbox   = (const float*)d_in[3];
  const int*   glab   = (const int*)d_in[4];
  float* part = (float*)d_ws;                 // PART_N floats
  int*   cnt  = (int*)(part + PART_N);        // 4B arrival counter

  hipMemsetAsync((void*)cnt, 0, sizeof(int), stream);  // ws is poisoned
  yolo_fused<<<dim3(NBLK), 256, 0, stream>>>(pconf, pcls, ptxywh, gbox, glab,
                                             part, cnt, (float*)d_out);
}

// Round 4
// 158.127 us; speedup vs baseline: 1.5017x; 1.0166x over previous
//
#include <hip/hip_runtime.h>
#include <math.h>

#define BATCH 32
#define NGT 20
#define HWA 10647
#define NCLS 80
#define NMATCH 32                   // one match block per batch
#define NDENSE 167                  // 167*256*2 = 85504 >= 85176 float4s
#define NBLK (NMATCH + NDENSE)      // 199 blocks — fits one scheduling wave
#define TOT_F4 ((BATCH * HWA) / 4)  // 340704/4 = 85176 (exact)
#define FP16_EPS 0.0009765625f
#define BCE_EPS 1e-6f

__device__ __constant__ float ANCS[9][2] = {
    {0.024f, 0.031f}, {0.038f, 0.072f}, {0.079f, 0.055f},
    {0.072f, 0.147f}, {0.149f, 0.108f}, {0.142f, 0.286f},
    {0.279f, 0.216f}, {0.375f, 0.476f}, {0.897f, 0.784f}};

// Fast device math (v_exp/v_log/v_rcp). Verified absmax 0.0 through R3
// vs threshold 1.79 — huge slack.
__device__ __forceinline__ float flog(float x) { return __logf(x); }
__device__ __forceinline__ float fsig(float x) {
  return __builtin_amdgcn_rcpf(1.0f + __expf(-x));
}

// Matching state per HWA row, packed into one int resolved by atomicMax:
//   bits [31:16] = priority (2p+1 for the "-1" col0 write, 2p+2 for the
//                  positive full-row write at scan step p)
//   bit  [15]    = is-positive-write
//   bits [7:0]   = rec = i*9 + a  (GT index i, anchor id a)
// cell == 0 <=> never written <=> gconf == 0 (negative row).
// atomicMax reproduces the reference scan's last-writer-wins exactly
// (verified absmax 0.0 through R3).
//
// Structure: 32 match blocks (one per batch, full-HWA cell array in LDS) +
// 167 dense blocks streaming sigmoid(pconf)^2 over ALL rows (2 float4 each);
// matched rows get a sparse correction. sum_neg = dense - corrections;
// cnt_neg = B*HWA - n_special.
//
// Schedule history (all absmax 0.0):
//   R0  512-blk 2-dispatch ................. 153.3 us
//   R1  365-blk 2-dispatch ................. 158.4 us
//   R2  cooperative grid.sync() ............ 237.5 us (sync alone ~75 us!)
//   R3  memset + last-block-done 1-dispatch  160.7 us
// All non-R2 variants are within harness noise (+/-4 us of the ~130 us
// reset-traffic floor). R4: leanest schedule — 199-blk main + 1-blk final,
// no memset, no atomic protocol.

__global__ __launch_bounds__(256) void yolo_main(
    const float* __restrict__ pconf,   // [B, HWA, 1]
    const float* __restrict__ pcls,    // [B, HWA, 80]
    const float* __restrict__ ptxywh,  // [B, HWA, 4]
    const float* __restrict__ gbox,    // [B, NGT, 4]
    const int* __restrict__ glab,      // [B, NGT]
    float* __restrict__ part)          // [8*NMATCH + NDENSE] partials
{
  const int tid = threadIdx.x;
  const int blk = blockIdx.x;

  __shared__ int cell[HWA];            // 42588 B
  __shared__ int pos_list[256];
  __shared__ int special[256];
  __shared__ float s_cx[NGT], s_cy[NGT], s_w[NGT], s_h[NGT], s_wt[NGT];
  __shared__ int s_a[NGT], s_lab[NGT], s_idx[NGT][3];
  __shared__ int s_np, s_nsp;
  __shared__ float red[4][8];

  if (blk >= NMATCH) {
    // ---- dense conf pass: streaming sum of sigmoid(pconf)^2, all rows ----
    int d = blk - NMATCH;
    int f0 = d * 256 + tid;
    int f1 = f0 + NDENSE * 256;
    float sum = 0.f;
    if (f0 < TOT_F4) {
      float4 v = ((const float4*)pconf)[f0];
      float s0 = fsig(v.x), s1 = fsig(v.y), s2 = fsig(v.z), s3 = fsig(v.w);
      sum += s0 * s0 + s1 * s1 + s2 * s2 + s3 * s3;
    }
    if (f1 < TOT_F4) {
      float4 v = ((const float4*)pconf)[f1];
      float s0 = fsig(v.x), s1 = fsig(v.y), s2 = fsig(v.z), s3 = fsig(v.w);
      sum += s0 * s0 + s1 * s1 + s2 * s2 + s3 * s3;
    }
    int lane = tid & 63, wv = tid >> 6;
    for (int o = 32; o > 0; o >>= 1) sum += __shfl_down(sum, o, 64);
    if (lane == 0) red[wv][0] = sum;
    __syncthreads();
    if (tid == 0)
      part[8 * NMATCH + d] = red[0][0] + red[1][0] + red[2][0] + red[3][0];
    return;
  }

  // ================= match path: batch b = blk =================
  const int b = blk;

  for (int r = tid; r < HWA; r += 256) cell[r] = 0;
  if (tid == 0) { s_np = 0; s_nsp = 0; }
  if (tid < NGT) {
    const float* gb = gbox + (b * NGT + tid) * 4;
    float l = gb[0], t = gb[1], r = gb[2], bo = gb[3];
    float cx = (l + r) * 0.5f, cy = (t + bo) * 0.5f;
    float w = r - l, h = bo - t;
    s_cx[tid] = cx; s_cy[tid] = cy; s_w[tid] = w; s_h[tid] = h;
    s_wt[tid] = 2.0f - w * h;
    s_lab[tid] = glab[b * NGT + tid];
    // argmax over 9 ratios: precise division (decision bits must match).
    float best = -1e30f; int bi = 0;
    for (int a = 0; a < 9; ++a) {
      float inter = fminf(w, ANCS[a][0]) * fminf(h, ANCS[a][1]);
      float uni = w * h + ANCS[a][0] * ANCS[a][1] - inter;
      float ratio = inter / uni;
      if (ratio > best) { best = ratio; bi = a; }  // first max == argmax
    }
    s_a[tid] = bi;
    const int GR[3] = {52, 26, 13};
    const int OF[3] = {0, 2704, 3380};
    for (int j = 0; j < 3; ++j) {
      int col = (int)(cx * (float)GR[j]);   // trunc, matches astype(int32)
      int row = (int)(cy * (float)GR[j]);
      s_idx[tid][j] = (OF[j] + row * GR[j] + col) * 3;
    }
  }
  __syncthreads();

  // ---- the 400-step scan via priority atomicMax, full array ----
  for (int p = tid; p < NGT * NGT; p += 256) {
    int i = p / NGT, k = p - i * NGT;
    int a = s_a[k];
    int ceng = a / 3;
    int pn = (2 * p + 1) << 16;
    int pp = ((2 * p + 2) << 16) | (1 << 15) | (i * 9 + a);
    for (int j = 0; j < 3; ++j) {
      int idx = s_idx[i][j];
      atomicMax(&cell[idx], pn);
      atomicMax(&cell[idx + 1], pn);
      atomicMax(&cell[idx + 2], pn);
      if (ceng == j) atomicMax(&cell[idx + (a - ceng * 3)], pp);
    }
  }
  __syncthreads();

  // ---- compact special rows (cell != 0) and positives ----
  // <= 20 GT * 9 window cells = 180 distinct -> 256 slots is safe.
  for (int r = tid; r < HWA; r += 256) {
    int c = cell[r];
    if (c != 0) {
      int slot = atomicAdd(&s_nsp, 1);
      int pk = ((c & 0xFF) << 16) | r;
      if (c & (1 << 15)) {
        pk |= (int)0x80000000;
        int ps = atomicAdd(&s_np, 1);
        pos_list[ps] = ((c & 0xFF) << 16) | r;
      }
      special[slot] = pk;
    }
  }
  __syncthreads();
  const int NSP = s_nsp, P = s_np;

  // ---- sparse conf corrections over special rows ----
  float possum = 0.f, negcorr = 0.f; int cnt_pos = 0;
  for (int q = tid; q < NSP; q += 256) {
    int pk = special[q];
    int r = pk & 0xFFFF;
    float s = fsig(pconf[(size_t)b * HWA + r]);
    negcorr += s * s;                      // this row is NOT a negative
    if (pk < 0) {                          // positive row
      float d = s - 1.0f; possum += d * d; cnt_pos++;
    }
  }

  // ---- sparse class BCE over positive rows ----
  float cls_sum = 0.f;
  for (int idx = tid; idx < P * NCLS; idx += 256) {
    int pr = idx / NCLS, c = idx - pr * NCLS;
    int pk = pos_list[pr];
    int r = pk & 0xFFFF, rec = pk >> 16;
    int i = rec / 9;
    int lab = s_lab[i] - 1;
    float x = pcls[((size_t)b * HWA + r) * NCLS + c];
    float s = fsig(x);
    s = fminf(fmaxf(s, BCE_EPS), 1.0f - BCE_EPS);
    float g = (c == lab) ? 1.0f : 0.0f;
    cls_sum += -(g * flog(s) + (1.0f - g) * flog(1.0f - s));
  }

  // ---- sparse txty (BCE) + twth (L2) over positive rows ----
  float txty_sum = 0.f, twth_sum = 0.f;
  for (int q = tid; q < P; q += 256) {
    int pk = pos_list[q];
    int r = pk & 0xFFFF, rec = pk >> 16;
    int i = rec / 9, a = rec - i * 9;
    int ceng = a / 3;
    const int GR[3] = {52, 26, 13};
    float grid = (float)GR[ceng];
    float cx = s_cx[i], cy = s_cy[i];
    int col = (int)(cx * grid), row = (int)(cy * grid);
    float tx = (cx - (float)col / grid) * grid;
    float ty = (cy - (float)row / grid) * grid;
    float twx = flog(s_w[i] / ANCS[a][0]);
    float twy = flog(s_h[i] / ANCS[a][1]);
    float wgt = s_wt[i];
    const float* pt = ptxywh + ((size_t)b * HWA + r) * 4;
    float s0 = fsig(pt[0]);
    float s1 = fsig(pt[1]);
    s0 = fminf(fmaxf(s0, BCE_EPS), 1.0f - BCE_EPS);
    s1 = fminf(fmaxf(s1, BCE_EPS), 1.0f - BCE_EPS);
    float b0 = -(tx * flog(s0) + (1.0f - tx) * flog(1.0f - s0));
    float b1 = -(ty * flog(s1) + (1.0f - ty) * flog(1.0f - s1));
    txty_sum += (b0 + b1) * wgt;
    float d2 = pt[2] - twx, d3 = pt[3] - twy;
    twth_sum += (d2 * d2 + d3 * d3) * wgt;
  }

  // ---- block reduce 6 partials, finalize per-batch row ----
  float v[6] = {possum, negcorr, (float)cnt_pos, cls_sum, txty_sum, twth_sum};
  int lane = tid & 63, wv = tid >> 6;
  for (int m = 0; m < 6; ++m) {
    float x = v[m];
    for (int o = 32; o > 0; o >>= 1) x += __shfl_down(x, o, 64);
    if (lane == 0) red[wv][m] = x;
  }
  __syncthreads();
  if (tid == 0) {
    float t[6];
    for (int m = 0; m < 6; ++m)
      t[m] = red[0][m] + red[1][m] + red[2][m] + red[3][m];
    float np = fmaxf(t[2], FP16_EPS);   // nums_pos clamp, per batch
    float rnp = 1.0f / np;
    float* w = part + b * 8;
    w[0] = t[0];            // sum_pos
    w[1] = t[1];            // neg correction (sum s^2 over special rows)
    w[2] = t[2];            // cnt_pos
    w[3] = (float)NSP;      // n_special (pos + ignore rows)
    w[4] = t[3] * rnp;      // l_cls_b
    w[5] = t[4] * rnp;      // l_txty_b
    w[6] = t[5] * rnp;      // l_twth_b
  }
}

__global__ __launch_bounds__(256) void yolo_final(
    const float* __restrict__ part, float* __restrict__ out) {
  const int t = threadIdx.x;
  __shared__ float red[4][8];
  float acc[8];
#pragma unroll
  for (int m = 0; m < 8; ++m) acc[m] = 0.f;
  if (t < NDENSE) acc[0] = part[8 * NMATCH + t];      // dense partial sums
  if (t < NMATCH) {
    const float* w = part + t * 8;
#pragma unroll
    for (int m = 0; m < 7; ++m) acc[m + 1] = w[m];
  }
  int lane = t & 63, wv = t >> 6;
#pragma unroll
  for (int m = 0; m < 8; ++m) {
    float x = acc[m];
    for (int o = 32; o > 0; o >>= 1) x += __shfl_down(x, o, 64);
    if (lane == 0) red[wv][m] = x;
  }
  __syncthreads();
  if (t == 0) {
    float s[8];
#pragma unroll
    for (int m = 0; m < 8; ++m)
      s[m] = red[0][m] + red[1][m] + red[2][m] + red[3][m];
    float dense = s[0], possum = s[1], negcorr = s[2];
    float cntpos = s[3], nsp = s[4];
    float sum_neg = dense - negcorr;
    float cnt_neg = (float)(BATCH * HWA) - nsp;
    out[0] = possum / cntpos * 30.0f + sum_neg / cnt_neg * 30.0f +
             (s[5] + s[6] + s[7]) * (1.0f / (float)BATCH);
  }
}

extern "C" void kernel_launch(void* const* d_in, const int* in_sizes, int n_in,
                              void* d_out, int out_size, void* d_ws,
                              size_t ws_size, hipStream_t stream) {
  const float* pconf  = (const float*)d_in[0];
  const float* pcls   = (const float*)d_in[1];
  const float* ptxywh = (const float*)d_in[2];
  const float* gbox   = (const float*)d_in[3];
  const int*   glab   = (const int*)d_in[4];
  float* part = (float*)d_ws;  // 8*NMATCH + NDENSE floats ~ 1.7 KB

  yolo_main<<<dim3(NBLK), 256, 0, stream>>>(pconf, pcls, ptxywh, gbox, glab,
                                            part);
  yolo_final<<<1, 256, 0, stream>>>(part, (float*)d_out);
}